// Round 1
// baseline (60009.442 us; speedup 1.0000x reference)
//
#include <hip/hip_runtime.h>

#define B_    32
#define TE_   256
#define TD_   256
#define ENC_  512
#define HID_  1024
#define ATT_  128
#define CCH_  32
#define KSZ_  31
#define PADK_ 15
#define OUT_  80
#define PRE_  256

// output regions (floats)
#define OUTS_OFF 0u
#define LOG_OFF  655360u      // B*OUT*TD
#define ATTW_OFF 663552u      // + B*TD

// workspace offsets (floats)
#define OFF_PM   0u           // [B][TE][ATT]            1048576
#define OFF_P0   1048576u     // [TD][B][PRE]            2097152
#define OFF_P1   3145728u     // [TD][B][PRE]            2097152
#define OFF_H0   5242880u     // 2 x [B][HID]            65536
#define OFF_H1   5308416u     // 2 x [B][HID]            65536
#define OFF_C0   5373952u     // [B][HID]                32768
#define OFF_C1   5406720u     // [B][HID]                32768
#define OFF_CUM  5439488u     // [B][TE]                 8192
#define OFF_ATTC 5447680u     // 2 x [B][ENC]            32768
#define OFF_WH   5480448u     // [B][ATT]                4096
#define OFF_SC   5484544u     // [B][TE]                 8192
#define OFF_M    5492736u     // [ATT][KSZ]              3968
#define OFF_END  5496704u

__device__ __forceinline__ float sigm(float x){ return 1.0f/(1.0f+__expf(-x)); }
__device__ __forceinline__ float tanh_f(float x){ float e = __expf(2.0f*x); return 1.0f - 2.0f/(e+1.0f); }

// ---------------- one-time kernels ----------------

__global__ void k_init(float* __restrict__ ws){
  unsigned n = OFF_END - OFF_H0;
  for (unsigned i = blockIdx.x*blockDim.x + threadIdx.x; i < n; i += gridDim.x*blockDim.x)
    ws[OFF_H0 + i] = 0.f;
}

// M[a][k] = sum_c U[a][c] * F[c][k]
__global__ void k_precm(const float* __restrict__ Uw, const float* __restrict__ Fw,
                        float* __restrict__ ws){
  float* M = ws + OFF_M;
  for (int idx = threadIdx.x; idx < ATT_*KSZ_; idx += blockDim.x){
    int a = idx / KSZ_, k = idx % KSZ_;
    float s = 0.f;
    for (int c = 0; c < CCH_; c++) s += Uw[a*CCH_+c]*Fw[c*KSZ_+k];
    M[idx] = s;
  }
}

// processed_memory: pm[b][s][a] = enc[b][s] . Vw[a] + Vb[a]
// grid 128 = b*4 + stile(64 rows), 256 thr = (a 0..127, sh 0..1)
__global__ __launch_bounds__(256) void k_pm(const float* __restrict__ enc,
    const float* __restrict__ Vw, const float* __restrict__ Vb, float* __restrict__ ws){
  float* pm = ws + OFF_PM;
  int b  = blockIdx.x >> 2;
  int s0 = (blockIdx.x & 3) << 6;
  int a  = threadIdx.x & 127;
  int sh = threadIdx.x >> 7;
  __shared__ float Vl[128*65];
  __shared__ float El[64*64];
  float acc[32];
  #pragma unroll
  for (int i=0;i<32;i++) acc[i]=0.f;
  for (int kc=0; kc<ENC_; kc+=64){
    for (int i=threadIdx.x; i<128*64; i+=256){
      int aa = i>>6, kk = i&63;
      Vl[aa*65+kk] = Vw[aa*ENC_ + kc + kk];
    }
    for (int i=threadIdx.x; i<64*64; i+=256){
      int ss = i>>6, kk = i&63;
      El[i] = enc[(size_t)(b*TE_ + s0 + ss)*ENC_ + kc + kk];
    }
    __syncthreads();
    for (int k=0;k<64;k++){
      float va = Vl[a*65+k];
      const float* er = &El[(sh*32)*64 + k];
      #pragma unroll
      for (int s=0;s<32;s++) acc[s] += va * er[s*64];
    }
    __syncthreads();
  }
  float bb = Vb[a];
  for (int s=0;s<32;s++)
    pm[(size_t)(b*TE_ + s0 + sh*32 + s)*ATT_ + a] = acc[s] + bb;
}

// prenet stage 0 for all t: p0[t][b][j] = relu(prev.w0[j]+b0)*m0
__global__ __launch_bounds__(256) void k_pre0(const float* __restrict__ tgt,
    const float* __restrict__ w0, const float* __restrict__ b0,
    const float* __restrict__ masks, float* __restrict__ ws){
  int t = blockIdx.x;
  int j = threadIdx.x;
  float* p0 = ws + OFF_P0 + (size_t)t*B_*PRE_;
  __shared__ float xl[B_*OUT_];
  for (int i=threadIdx.x; i<B_*OUT_; i+=256){
    int b = i/OUT_, o = i%OUT_;
    xl[i] = (t==0) ? 0.f : tgt[((size_t)b*TD_ + (t-1))*OUT_ + o];
  }
  __syncthreads();
  float bj = b0[j];
  const float* wr = w0 + j*OUT_;
  float w[OUT_];
  #pragma unroll
  for (int o=0;o<OUT_;o++) w[o] = wr[o];
  for (int b=0;b<B_;b++){
    float a0=0,a1=0,a2=0,a3=0;
    const float* x = &xl[b*OUT_];
    #pragma unroll
    for (int o=0;o<OUT_;o+=4){
      a0+=w[o]*x[o]; a1+=w[o+1]*x[o+1]; a2+=w[o+2]*x[o+2]; a3+=w[o+3]*x[o+3];
    }
    float m = masks[(((size_t)t*2+0)*B_+b)*PRE_ + j];
    p0[b*PRE_ + j] = fmaxf(bj+a0+a1+a2+a3, 0.f) * m;
  }
}

// prenet stage 1: p1[t][b][j] = relu(p0.w1[j]+b1)*m1
__global__ __launch_bounds__(256) void k_pre1(const float* __restrict__ w1,
    const float* __restrict__ b1, const float* __restrict__ masks, float* __restrict__ ws){
  int t = blockIdx.x;
  int j = threadIdx.x;
  const float* p0 = ws + OFF_P0 + (size_t)t*B_*PRE_;
  float* p1 = ws + OFF_P1 + (size_t)t*B_*PRE_;
  __shared__ float xl[B_*PRE_];
  for (int i=threadIdx.x; i<B_*PRE_; i+=256) xl[i] = p0[i];
  __syncthreads();
  float bj = b1[j];
  const float4* wr = (const float4*)(w1 + j*PRE_);
  float acc[32];
  #pragma unroll
  for (int i=0;i<32;i++) acc[i]=0.f;
  for (int o4=0;o4<64;o4++){
    float4 w = wr[o4];
    #pragma unroll
    for (int b=0;b<32;b++){
      const float4 xv = *(const float4*)&xl[b*PRE_ + o4*4];
      acc[b] += w.x*xv.x + w.y*xv.y + w.z*xv.z + w.w*xv.w;
    }
  }
  for (int b=0;b<32;b++){
    float m = masks[(((size_t)t*2+1)*B_+b)*PRE_ + j];
    p1[b*PRE_ + j] = fmaxf(bj+acc[b], 0.f) * m;
  }
}

// ---------------- per-step kernels ----------------

// attention scores: grid 256 = b*8 + ptile(32 pos), thr 256 = (pos_l 0..31, q 0..7)
__global__ __launch_bounds__(256) void k_att1(int t, const int* __restrict__ lens,
    const float* __restrict__ ww, const float* __restrict__ wb, float* __restrict__ ws){
  int b  = blockIdx.x >> 3;
  int pt = blockIdx.x & 7;
  const float* pm  = ws + OFF_PM;
  const float* cum = ws + OFF_CUM + b*TE_;
  const float* Mg  = ws + OFF_M;
  const float* whg = ws + OFF_WH + b*ATT_;
  float* sc_out = ws + OFF_SC + b*TE_;
  __shared__ float apad[TE_ + 2*PADK_ + 2];
  __shared__ float Ml[ATT_*KSZ_];
  __shared__ float whl[ATT_];
  __shared__ float wl[ATT_];
  __shared__ float ps[256];
  int len = lens[b];
  for (int i=threadIdx.x; i<TE_+2*PADK_; i+=256){
    int p = i - PADK_;
    apad[i] = (p>=0 && p<TE_) ? ((t==0) ? ((p<len)? 1.0f/(float)len : 0.f) : cum[p]) : 0.f;
  }
  for (int i=threadIdx.x; i<ATT_*KSZ_; i+=256) Ml[i] = Mg[i];
  if (threadIdx.x < ATT_){ whl[threadIdx.x] = whg[threadIdx.x]; wl[threadIdx.x] = ww[threadIdx.x]; }
  __syncthreads();
  int pos_l = threadIdx.x & 31;
  int q     = threadIdx.x >> 5;
  int pos   = pt*32 + pos_l;
  const float* pmrow = pm + (size_t)(b*TE_+pos)*ATT_;
  const float* ap = apad + pos;
  float part = 0.f;
  for (int aa=0; aa<16; aa++){
    int a = q*16 + aa;
    const float* mr = Ml + a*KSZ_;
    float u0 = pmrow[a] + whl[a];
    float u1=0.f, u2=0.f, u3=0.f;
    #pragma unroll
    for (int k=0;k<28;k+=4){
      u0 += ap[k]*mr[k]; u1 += ap[k+1]*mr[k+1];
      u2 += ap[k+2]*mr[k+2]; u3 += ap[k+3]*mr[k+3];
    }
    u0 += ap[28]*mr[28]; u1 += ap[29]*mr[29]; u2 += ap[30]*mr[30];
    part += tanh_f(u0+u1+u2+u3) * wl[a];
  }
  ps[threadIdx.x] = part;
  __syncthreads();
  if (threadIdx.x < 32){
    int p = pt*32 + threadIdx.x;
    float s = wb[0];
    #pragma unroll
    for (int qq=0; qq<8; qq++) s += ps[qq*32 + threadIdx.x];
    if (p >= len) s = -1.0e9f;
    sc_out[p] = s;
  }
}

// softmax + att_c + cum + att_ws  AND  outputs for step t-1.
// grid 70: blk<64 attention (b=blk>>1, eh=blk&1); blk 64..69 output rows.
__global__ __launch_bounds__(512) void k_att2(int t,
    const float* __restrict__ enc, const float* __restrict__ featw,
    const float* __restrict__ probw, const float* __restrict__ probb,
    float* __restrict__ ws, float* __restrict__ out){
  __shared__ float sm[4352];
  int blk = blockIdx.x;
  int tid = threadIdx.x;
  if (blk < 64){
    if (t >= TD_) return;
    int b = blk >> 1, eh = blk & 1;
    float* sl  = sm;        // 256
    float* red = sm + 256;  // 128
    float* awl = sm + 384;  // 256
    float* ps2 = sm + 640;  // 512
    const float* sc = ws + OFF_SC + b*TE_;
    if (tid < 256) sl[tid] = sc[tid];
    __syncthreads();
    if (tid < 128) red[tid] = fmaxf(sl[tid], sl[tid+128]);
    __syncthreads();
    if (tid < 64){
      float v = fmaxf(red[tid], red[tid+64]);
      #pragma unroll
      for (int off=32; off>0; off>>=1) v = fmaxf(v, __shfl_down(v, off));
      if (tid == 0) red[0] = v;
    }
    __syncthreads();
    float m = red[0];
    if (tid < 256) sl[tid] = __expf(sl[tid] - m);
    __syncthreads();
    if (tid < 128) red[tid] = sl[tid] + sl[tid+128];
    __syncthreads();
    if (tid < 64){
      float v = red[tid] + red[tid+64];
      #pragma unroll
      for (int off=32; off>0; off>>=1) v += __shfl_down(v, off);
      if (tid == 0) red[0] = v;
    }
    __syncthreads();
    float inv = 1.0f / red[0];
    if (tid < 256){
      float aw = sl[tid] * inv;
      awl[tid] = aw;
      if (eh == 0){
        ws[OFF_CUM + b*TE_ + tid] += aw;
        out[ATTW_OFF + (size_t)(b*TD_ + t)*TE_ + tid] = aw;
      }
    }
    __syncthreads();
    int el = tid & 255, ph = tid >> 8;
    int e_ = eh*256 + el;
    const float* ep = enc + (size_t)b*TE_*ENC_ + e_;
    float a0 = 0.f, a1 = 0.f;
    for (int p = ph*128; p < ph*128+128; p += 2){
      a0 += awl[p]   * ep[(size_t)p*ENC_];
      a1 += awl[p+1] * ep[(size_t)(p+1)*ENC_];
    }
    ps2[ph*256 + el] = a0 + a1;
    __syncthreads();
    if (tid < 256)
      ws[OFF_ATTC + (size_t)(t&1)*16384 + b*ENC_ + eh*256 + tid] = ps2[tid] + ps2[256+tid];
  } else {
    if (t == 0) return;
    int ob = blk - 64;
    int b  = tid & 31;
    int rl = tid >> 5;            // 0..15
    int r  = ob*16 + rl;          // 0..95 (80 = prob row, 81.. idle)
    const float* h1p = ws + OFF_H1 + (size_t)(t&1)*32768;
    const float* acp = ws + OFF_ATTC + (size_t)((t-1)&1)*16384;
    float* xl = sm;               // [128][33] = 4224
    float a0=0,a1=0,a2=0,a3=0;
    const float* wr = (r < OUT_) ? (featw + (size_t)r*1536) : probw;
    for (int c=0; c<12; c++){
      int kg0 = c*128;
      for (int i=tid; i<4096; i+=512){
        int bl = i >> 7, k = i & 127;
        int kg = kg0 + k;
        float v = (kg < HID_) ? h1p[bl*HID_ + kg] : acp[bl*ENC_ + (kg-HID_)];
        xl[k*33 + bl] = v;
      }
      __syncthreads();
      if (r <= OUT_){
        #pragma unroll 8
        for (int k=0;k<128;k+=4){
          const float4 w = *(const float4*)(wr + kg0 + k);
          a0 += w.x * xl[(k+0)*33+b];
          a1 += w.y * xl[(k+1)*33+b];
          a2 += w.z * xl[(k+2)*33+b];
          a3 += w.w * xl[(k+3)*33+b];
        }
      }
      __syncthreads();
    }
    float v = a0+a1+a2+a3;
    int tt = t-1;
    if (r < OUT_)       out[(size_t)(b*OUT_ + r)*TD_ + tt] = v;
    else if (r == OUT_) out[LOG_OFF + b*TD_ + tt] = v + probb[0];
  }
}

// LSTM0: x = [att_c(512), p1(256), h0(1024)], K=1792.
// grid 256 (u-tile 4), thr 512 = (b 0..31, ul 0..3, kq 0..3)
__global__ __launch_bounds__(512) void k_lstm0(int t,
    const float* __restrict__ wih, const float* __restrict__ whh,
    const float* __restrict__ bih, const float* __restrict__ bhh,
    float* __restrict__ ws){
  int tid = threadIdx.x;
  int b  = tid & 31;
  int ul = (tid >> 5) & 3;
  int kq = tid >> 7;
  int u0 = blockIdx.x * 4;
  const float* attc = ws + OFF_ATTC + (size_t)(t&1)*16384;
  const float* p1   = ws + OFF_P1 + (size_t)t*B_*PRE_;
  const float* h_rd = ws + OFF_H0 + (size_t)(t&1)*32768;
  float*       h_wr = ws + OFF_H0 + (size_t)((t&1)^1)*32768;
  float*       c_st = ws + OFF_C0;
  __shared__ float xl[128*33];
  __shared__ float gl[2048];
  float A0[4]={0,0,0,0}, A1[4]={0,0,0,0}, A2[4]={0,0,0,0}, A3[4]={0,0,0,0};
  for (int c=0; c<14; c++){
    int kg0 = c*128;
    for (int i=tid; i<4096; i+=512){
      int bl = i >> 7, k = i & 127;
      int kg = kg0 + k;
      float v;
      if (kg < ENC_)            v = attc[bl*ENC_ + kg];
      else if (kg < ENC_+PRE_)  v = p1[bl*PRE_ + (kg - ENC_)];
      else                      v = h_rd[bl*HID_ + (kg - ENC_ - PRE_)];
      xl[k*33 + bl] = v;
    }
    __syncthreads();
    int colbase = kg0 + kq*32;
    #pragma unroll
    for (int g=0; g<4; g++){
      int row = g*HID_ + u0 + ul;
      const float4* w4 = (const float4*)((kg0 < 768)
          ? (wih + (size_t)row*768  + colbase)
          : (whh + (size_t)row*HID_ + (colbase - 768)));
      #pragma unroll
      for (int k4=0; k4<8; k4++){
        float4 w = w4[k4];
        int k = kq*32 + k4*4;
        A0[g] += w.x * xl[(k+0)*33 + b];
        A1[g] += w.y * xl[(k+1)*33 + b];
        A2[g] += w.z * xl[(k+2)*33 + b];
        A3[g] += w.w * xl[(k+3)*33 + b];
      }
    }
    __syncthreads();
  }
  #pragma unroll
  for (int g=0; g<4; g++)
    gl[((kq*4+ul)*4 + g)*32 + b] = A0[g]+A1[g]+A2[g]+A3[g];
  __syncthreads();
  if (tid < 128){
    int bb = tid & 31, uu = tid >> 5;
    int u = u0 + uu;
    float gv[4];
    #pragma unroll
    for (int g=0; g<4; g++){
      float s = 0.f;
      #pragma unroll
      for (int kk=0; kk<4; kk++) s += gl[((kk*4+uu)*4 + g)*32 + bb];
      gv[g] = s + bih[g*HID_+u] + bhh[g*HID_+u];
    }
    float c_old = c_st[bb*HID_+u];
    float h_old = h_rd[bb*HID_+u];
    float cn = sigm(gv[1])*c_old + sigm(gv[0])*tanh_f(gv[2]);
    float hn = sigm(gv[3])*tanh_f(cn);
    c_st[bb*HID_+u] = 0.1f*c_old + 0.9f*cn;
    h_wr[bb*HID_+u] = 0.1f*h_old + 0.9f*hn;
  }
}

// LSTM1: x = [h0_new(1024), h1(1024)], K=2048. grid 256 main + 32 Wh blocks.
__global__ __launch_bounds__(512) void k_lstm1(int t,
    const float* __restrict__ wih, const float* __restrict__ whh,
    const float* __restrict__ bih, const float* __restrict__ bhh,
    const float* __restrict__ Ww, float* __restrict__ ws){
  int tid = threadIdx.x;
  const float* h0n = ws + OFF_H0 + (size_t)((t&1)^1)*32768;
  __shared__ float xl[128*33];
  __shared__ float gl[2048];
  if (blockIdx.x >= 256){
    // Wh[b][a] = h0_new[b] . Ww[a]  (for attention at step t+1)
    int bb = blockIdx.x - 256;    // 0..31, a-tile 4
    int b  = tid & 31;
    int qq = (tid >> 5) & 3;
    int al = tid >> 7;
    int a  = bb*4 + al;
    float s0=0,s1=0,s2=0,s3=0;
    for (int c=0; c<8; c++){
      int kg0 = c*128;
      for (int i=tid; i<4096; i+=512){
        int bl = i>>7, k = i&127;
        xl[k*33+bl] = h0n[bl*HID_ + kg0 + k];
      }
      __syncthreads();
      const float4* w4 = (const float4*)(Ww + (size_t)a*HID_ + kg0 + qq*32);
      #pragma unroll
      for (int k4=0;k4<8;k4++){
        float4 w = w4[k4];
        int k = qq*32 + k4*4;
        s0 += w.x*xl[(k+0)*33+b]; s1 += w.y*xl[(k+1)*33+b];
        s2 += w.z*xl[(k+2)*33+b]; s3 += w.w*xl[(k+3)*33+b];
      }
      __syncthreads();
    }
    gl[(qq*4+al)*32 + b] = s0+s1+s2+s3;
    __syncthreads();
    if (tid < 128){
      int b2 = tid & 31, a2 = tid >> 5;
      float s = 0.f;
      #pragma unroll
      for (int q2=0;q2<4;q2++) s += gl[(q2*4+a2)*32 + b2];
      ws[OFF_WH + b2*ATT_ + (bb*4+a2)] = s;
    }
    return;
  }
  int b  = tid & 31;
  int ul = (tid >> 5) & 3;
  int kq = tid >> 7;
  int u0 = blockIdx.x * 4;
  const float* h_rd = ws + OFF_H1 + (size_t)(t&1)*32768;
  float*       h_wr = ws + OFF_H1 + (size_t)((t&1)^1)*32768;
  float*       c_st = ws + OFF_C1;
  float A0[4]={0,0,0,0}, A1[4]={0,0,0,0}, A2[4]={0,0,0,0}, A3[4]={0,0,0,0};
  for (int c=0; c<16; c++){
    int kg0 = c*128;
    for (int i=tid; i<4096; i+=512){
      int bl = i >> 7, k = i & 127;
      int kg = kg0 + k;
      float v = (kg < HID_) ? h0n[bl*HID_ + kg] : h_rd[bl*HID_ + (kg - HID_)];
      xl[k*33 + bl] = v;
    }
    __syncthreads();
    int colbase = kg0 + kq*32;
    #pragma unroll
    for (int g=0; g<4; g++){
      int row = g*HID_ + u0 + ul;
      const float4* w4 = (const float4*)((kg0 < HID_)
          ? (wih + (size_t)row*HID_ + colbase)
          : (whh + (size_t)row*HID_ + (colbase - HID_)));
      #pragma unroll
      for (int k4=0; k4<8; k4++){
        float4 w = w4[k4];
        int k = kq*32 + k4*4;
        A0[g] += w.x * xl[(k+0)*33 + b];
        A1[g] += w.y * xl[(k+1)*33 + b];
        A2[g] += w.z * xl[(k+2)*33 + b];
        A3[g] += w.w * xl[(k+3)*33 + b];
      }
    }
    __syncthreads();
  }
  #pragma unroll
  for (int g=0; g<4; g++)
    gl[((kq*4+ul)*4 + g)*32 + b] = A0[g]+A1[g]+A2[g]+A3[g];
  __syncthreads();
  if (tid < 128){
    int bb = tid & 31, uu = tid >> 5;
    int u = u0 + uu;
    float gv[4];
    #pragma unroll
    for (int g=0; g<4; g++){
      float s = 0.f;
      #pragma unroll
      for (int kk=0; kk<4; kk++) s += gl[((kk*4+uu)*4 + g)*32 + bb];
      gv[g] = s + bih[g*HID_+u] + bhh[g*HID_+u];
    }
    float c_old = c_st[bb*HID_+u];
    float h_old = h_rd[bb*HID_+u];
    float cn = sigm(gv[1])*c_old + sigm(gv[0])*tanh_f(gv[2]);
    float hn = sigm(gv[3])*tanh_f(cn);
    c_st[bb*HID_+u] = 0.1f*c_old + 0.9f*cn;
    h_wr[bb*HID_+u] = 0.1f*h_old + 0.9f*hn;
  }
}

extern "C" void kernel_launch(void* const* d_in, const int* in_sizes, int n_in,
                              void* d_out, int out_size, void* d_ws, size_t ws_size,
                              hipStream_t stream){
  const float* enc   = (const float*)d_in[0];
  const float* tgt   = (const float*)d_in[1];
  const float* masks = (const float*)d_in[2];
  const int*   lens  = (const int*)  d_in[3];
  const float* Vw    = (const float*)d_in[4];
  const float* Vb    = (const float*)d_in[5];
  const float* Ww    = (const float*)d_in[6];
  const float* Uw    = (const float*)d_in[7];
  const float* Fw    = (const float*)d_in[8];
  const float* ww    = (const float*)d_in[9];
  const float* wb    = (const float*)d_in[10];
  const float* pw0   = (const float*)d_in[11];
  const float* pb0   = (const float*)d_in[12];
  const float* pw1   = (const float*)d_in[13];
  const float* pb1   = (const float*)d_in[14];
  const float* l0wih = (const float*)d_in[15];
  const float* l0whh = (const float*)d_in[16];
  const float* l0bih = (const float*)d_in[17];
  const float* l0bhh = (const float*)d_in[18];
  const float* l1wih = (const float*)d_in[19];
  const float* l1whh = (const float*)d_in[20];
  const float* l1bih = (const float*)d_in[21];
  const float* l1bhh = (const float*)d_in[22];
  const float* featw = (const float*)d_in[23];
  const float* probw = (const float*)d_in[24];
  const float* probb = (const float*)d_in[25];
  float* ws  = (float*)d_ws;
  float* out = (float*)d_out;

  k_init <<<256,256,0,stream>>>(ws);
  k_precm<<<1,  256,0,stream>>>(Uw, Fw, ws);
  k_pm   <<<128,256,0,stream>>>(enc, Vw, Vb, ws);
  k_pre0 <<<256,256,0,stream>>>(tgt, pw0, pb0, masks, ws);
  k_pre1 <<<256,256,0,stream>>>(pw1, pb1, masks, ws);

  for (int t = 0; t < TD_; t++){
    k_att1 <<<256,256,0,stream>>>(t, lens, ww, wb, ws);
    k_att2 <<<70, 512,0,stream>>>(t, enc, featw, probw, probb, ws, out);
    k_lstm0<<<256,512,0,stream>>>(t, l0wih, l0whh, l0bih, l0bhh, ws);
    k_lstm1<<<288,512,0,stream>>>(t, l1wih, l1whh, l1bih, l1bhh, Ww, ws);
  }
  // outputs for the final step (t-1 == 255)
  k_att2<<<70,512,0,stream>>>(TD_, enc, featw, probw, probb, ws, out);
}

// Round 2
// 28015.503 us; speedup vs baseline: 2.1420x; 2.1420x over previous
//
#include <hip/hip_runtime.h>

#define B_    32
#define TE_   256
#define TD_   256
#define ENC_  512
#define HID_  1024
#define ATT_  128
#define CCH_  32
#define KSZ_  31
#define OUT_  80
#define PRE_  256

// output regions (floats)
#define OUTS_OFF 0u
#define LOG_OFF  655360u      // B*OUT*TD
#define ATTW_OFF 663552u      // + B*TD

// workspace offsets (floats)
#define OFF_PM   0u           // [B][ATT][TE] (transposed!)  1048576
#define OFF_P0   1048576u     // [TD][B][PRE] (scratch; reused after prenet)
#define OFF_M    1048576u     //   [128*31] merged conv*U    (inside old P0)
#define OFF_H1T  1052672u     //   [B][1024] h1 state        (inside old P0)
#define OFF_P1   3145728u     // [TD][B][PRE]
#define OFF_XC0  5242880u     // [B][1792]  lstm0 x: attc|p1|h0
#define OFF_XC1  5300224u     // [B][2048]  lstm1 x: h0n|h1
#define OFF_C0   5365760u     // [B][1024]
#define OFF_C1   5398528u     // [B][1024]
#define OFF_CUM  5431296u     // [B][256]
#define OFF_ATTC 5439488u     // 2 x [B][512]
#define OFF_WH   5472256u     // [B][128]
#define OFF_END  5476352u

__device__ __forceinline__ float rcp_f(float x){ return __builtin_amdgcn_rcpf(x); }
__device__ __forceinline__ float sigm(float x){ return rcp_f(1.0f + __expf(-x)); }
__device__ __forceinline__ float tanh_f(float x){ float e = __expf(2.0f*x); return 1.0f - 2.0f*rcp_f(e+1.0f); }

// ---------------- one-time kernels ----------------

__global__ void k_init(float* __restrict__ ws){
  unsigned stride = gridDim.x*blockDim.x;
  unsigned i0 = blockIdx.x*blockDim.x + threadIdx.x;
  for (unsigned j = i0; j < (OFF_END - OFF_XC0); j += stride) ws[OFF_XC0 + j] = 0.f;
  for (unsigned j = i0; j < 32768u; j += stride) ws[OFF_H1T + j] = 0.f;
}

// M[a][k] = sum_c U[a][c] * F[c][k]
__global__ void k_precm(const float* __restrict__ Uw, const float* __restrict__ Fw,
                        float* __restrict__ ws){
  float* M = ws + OFF_M;
  for (int idx = threadIdx.x; idx < ATT_*KSZ_; idx += blockDim.x){
    int a = idx / KSZ_, k = idx % KSZ_;
    float s = 0.f;
    for (int c = 0; c < CCH_; c++) s += Uw[a*CCH_+c]*Fw[c*KSZ_+k];
    M[idx] = s;
  }
}

// processed_memory TRANSPOSED: pm[b][a][s] = enc[b][s].Vw[a] + Vb[a]
__global__ __launch_bounds__(256) void k_pm(const float* __restrict__ enc,
    const float* __restrict__ Vw, const float* __restrict__ Vb, float* __restrict__ ws){
  float* pm = ws + OFF_PM;
  int b  = blockIdx.x >> 2;
  int s0 = (blockIdx.x & 3) << 6;
  int a  = threadIdx.x & 127;
  int sh = threadIdx.x >> 7;
  __shared__ float Vl[128*65];
  __shared__ float El[64*64];
  float acc[32];
  #pragma unroll
  for (int i=0;i<32;i++) acc[i]=0.f;
  for (int kc=0; kc<ENC_; kc+=64){
    for (int i=threadIdx.x; i<128*64; i+=256){
      int aa = i>>6, kk = i&63;
      Vl[aa*65+kk] = Vw[aa*ENC_ + kc + kk];
    }
    for (int i=threadIdx.x; i<64*64; i+=256){
      int ss = i>>6, kk = i&63;
      El[i] = enc[(size_t)(b*TE_ + s0 + ss)*ENC_ + kc + kk];
    }
    __syncthreads();
    for (int k=0;k<64;k++){
      float va = Vl[a*65+k];
      const float* er = &El[(sh*32)*64 + k];
      #pragma unroll
      for (int s=0;s<32;s++) acc[s] += va * er[s*64];
    }
    __syncthreads();
  }
  float bb = Vb[a];
  for (int s=0;s<32;s++)
    pm[((size_t)b*128 + a)*256 + (s0 + sh*32 + s)] = acc[s] + bb;
}

// prenet stage 0
__global__ __launch_bounds__(256) void k_pre0(const float* __restrict__ tgt,
    const float* __restrict__ w0, const float* __restrict__ b0,
    const float* __restrict__ masks, float* __restrict__ ws){
  int t = blockIdx.x;
  int j = threadIdx.x;
  float* p0 = ws + OFF_P0 + (size_t)t*B_*PRE_;
  __shared__ float xl[B_*OUT_];
  for (int i=threadIdx.x; i<B_*OUT_; i+=256){
    int b = i/OUT_, o = i%OUT_;
    xl[i] = (t==0) ? 0.f : tgt[((size_t)b*TD_ + (t-1))*OUT_ + o];
  }
  __syncthreads();
  float bj = b0[j];
  const float* wr = w0 + j*OUT_;
  float w[OUT_];
  #pragma unroll
  for (int o=0;o<OUT_;o++) w[o] = wr[o];
  for (int b=0;b<B_;b++){
    float a0=0,a1=0,a2=0,a3=0;
    const float* x = &xl[b*OUT_];
    #pragma unroll
    for (int o=0;o<OUT_;o+=4){
      a0+=w[o]*x[o]; a1+=w[o+1]*x[o+1]; a2+=w[o+2]*x[o+2]; a3+=w[o+3]*x[o+3];
    }
    float m = masks[(((size_t)t*2+0)*B_+b)*PRE_ + j];
    p0[b*PRE_ + j] = fmaxf(bj+a0+a1+a2+a3, 0.f) * m;
  }
}

// prenet stage 1
__global__ __launch_bounds__(256) void k_pre1(const float* __restrict__ w1,
    const float* __restrict__ b1, const float* __restrict__ masks, float* __restrict__ ws){
  int t = blockIdx.x;
  int j = threadIdx.x;
  const float* p0 = ws + OFF_P0 + (size_t)t*B_*PRE_;
  float* p1 = ws + OFF_P1 + (size_t)t*B_*PRE_;
  __shared__ float xl[B_*PRE_];
  for (int i=threadIdx.x; i<B_*PRE_; i+=256) xl[i] = p0[i];
  __syncthreads();
  float bj = b1[j];
  const float4* wr = (const float4*)(w1 + j*PRE_);
  float acc[32];
  #pragma unroll
  for (int i=0;i<32;i++) acc[i]=0.f;
  for (int o4=0;o4<64;o4++){
    float4 w = wr[o4];
    #pragma unroll
    for (int b=0;b<32;b++){
      const float4 xv = *(const float4*)&xl[b*PRE_ + o4*4];
      acc[b] += w.x*xv.x + w.y*xv.y + w.z*xv.z + w.w*xv.w;
    }
  }
  for (int b=0;b<32;b++){
    float m = masks[(((size_t)t*2+1)*B_+b)*PRE_ + j];
    p1[b*PRE_ + j] = fmaxf(bj+acc[b], 0.f) * m;
  }
}

// ---------------- per-step kernels ----------------

// A: attention (blocks 0..31, one per batch) + outputs t-1 (32..55) + h1 copy (56..63)
__global__ __launch_bounds__(512) void k_att(int t, const float* __restrict__ enc,
    const int* __restrict__ lens, const float* __restrict__ ww, const float* __restrict__ wb,
    const float* __restrict__ featw, const float* __restrict__ probw,
    const float* __restrict__ probb, float* __restrict__ ws, float* __restrict__ out){
  __shared__ __align__(16) float apad[288];
  __shared__ __align__(16) float Ml[128*32];
  __shared__ __align__(16) float whl[128];
  __shared__ __align__(16) float wl[128];
  __shared__ __align__(16) float sc[256];
  __shared__ __align__(16) float awl[256];
  __shared__ __align__(16) float psq[2048];
  __shared__ __align__(16) float red2[128];
  __shared__ __align__(16) float ctxp[2048];
  __shared__ __align__(16) float redo[512];
  int blk = blockIdx.x, tid = threadIdx.x;
  if (blk < 32){
    if (t >= TD_) return;
    int b = blk;
    int len = lens[b];
    if (tid < 256)
      ws[OFF_XC0 + (size_t)b*1792 + 512 + tid] = ws[OFF_P1 + ((size_t)t*B_ + b)*PRE_ + tid];
    for (int i=tid; i<288; i+=512){
      int p = i - 15;
      float v = 0.f;
      if (p >= 0 && p < TE_) v = (t==0) ? ((p < len) ? 1.0f/(float)len : 0.f)
                                        : ws[OFF_CUM + b*TE_ + p];
      apad[i] = v;
    }
    for (int i=tid; i<128*31; i+=512) Ml[(i/31)*32 + (i%31)] = ws[OFF_M + i];
    if (tid < 128){ whl[tid] = ws[OFF_WH + b*128 + tid]; wl[tid] = ww[tid]; }
    __syncthreads();
    int pg = tid & 63, q = tid >> 6;
    float apw[36];
    #pragma unroll
    for (int i=0;i<36;i+=4) *(float4*)&apw[i] = *(const float4*)&apad[pg*4 + i];
    float part0=0, part1=0, part2=0, part3=0;
    const float* pmb = ws + OFF_PM + (size_t)b*128*256;
    for (int aa=0; aa<16; aa++){
      int a = q*16 + aa;
      const float* mr = Ml + a*32;
      float4 pv = *(const float4*)(pmb + (size_t)a*256 + pg*4);
      float wa = whl[a];
      float u0 = pv.x + wa, u1 = pv.y + wa, u2 = pv.z + wa, u3 = pv.w + wa;
      #pragma unroll
      for (int k=0;k<28;k+=4){
        float4 m4 = *(const float4*)(mr + k);
        u0 += m4.x*apw[k]   + m4.y*apw[k+1] + m4.z*apw[k+2] + m4.w*apw[k+3];
        u1 += m4.x*apw[k+1] + m4.y*apw[k+2] + m4.z*apw[k+3] + m4.w*apw[k+4];
        u2 += m4.x*apw[k+2] + m4.y*apw[k+3] + m4.z*apw[k+4] + m4.w*apw[k+5];
        u3 += m4.x*apw[k+3] + m4.y*apw[k+4] + m4.z*apw[k+5] + m4.w*apw[k+6];
      }
      float m28 = mr[28], m29 = mr[29], m30 = mr[30];
      u0 += m28*apw[28] + m29*apw[29] + m30*apw[30];
      u1 += m28*apw[29] + m29*apw[30] + m30*apw[31];
      u2 += m28*apw[30] + m29*apw[31] + m30*apw[32];
      u3 += m28*apw[31] + m29*apw[32] + m30*apw[33];
      float wv = wl[a];
      part0 += tanh_f(u0)*wv; part1 += tanh_f(u1)*wv;
      part2 += tanh_f(u2)*wv; part3 += tanh_f(u3)*wv;
    }
    float4 pp; pp.x = part0; pp.y = part1; pp.z = part2; pp.w = part3;
    *(float4*)&psq[tid*4] = pp;
    __syncthreads();
    if (tid < 256){
      float s = wb[0];
      int pgg = tid >> 2, d = tid & 3;
      #pragma unroll
      for (int qq=0;qq<8;qq++) s += psq[(qq*64 + pgg)*4 + d];
      sc[tid] = (tid >= len) ? -1.0e9f : s;
    }
    __syncthreads();
    if (tid < 128) red2[tid] = fmaxf(sc[tid], sc[tid+128]);
    __syncthreads();
    if (tid < 64){
      float v = fmaxf(red2[tid], red2[tid+64]);
      #pragma unroll
      for (int off=32; off>0; off>>=1) v = fmaxf(v, __shfl_down(v, off));
      if (tid==0) red2[0] = v;
    }
    __syncthreads();
    float mx = red2[0];
    if (tid < 256) awl[tid] = __expf(sc[tid]-mx);
    __syncthreads();
    if (tid < 128) red2[tid] = awl[tid] + awl[tid+128];
    __syncthreads();
    if (tid < 64){
      float v = red2[tid] + red2[tid+64];
      #pragma unroll
      for (int off=32; off>0; off>>=1) v += __shfl_down(v, off);
      if (tid==0) red2[0] = v;
    }
    __syncthreads();
    float inv = 1.0f/red2[0];
    if (tid < 256){
      float aw = awl[tid]*inv;
      awl[tid] = aw;
      ws[OFF_CUM + b*TE_ + tid] += aw;
      out[ATTW_OFF + ((size_t)b*TD_ + t)*TE_ + tid] = aw;
    }
    __syncthreads();
    int el = tid & 127, p4 = tid >> 7;
    float4 ca; ca.x=0; ca.y=0; ca.z=0; ca.w=0;
    const float* ep = enc + ((size_t)b*TE_ + p4*64)*ENC_ + el*4;
    for (int p=0;p<64;p++){
      float a = awl[p4*64+p];
      float4 ev = *(const float4*)(ep + (size_t)p*ENC_);
      ca.x += a*ev.x; ca.y += a*ev.y; ca.z += a*ev.z; ca.w += a*ev.w;
    }
    *(float4*)&ctxp[tid*4] = ca;
    __syncthreads();
    if (tid < 128){
      float4 s = *(const float4*)&ctxp[tid*4];
      #pragma unroll
      for (int g=1;g<4;g++){
        float4 o = *(const float4*)&ctxp[(g*128+tid)*4];
        s.x+=o.x; s.y+=o.y; s.z+=o.z; s.w+=o.w;
      }
      *(float4*)(ws + OFF_XC0 + (size_t)b*1792 + tid*4) = s;
      *(float4*)(ws + OFF_ATTC + (size_t)(t&1)*16384 + b*ENC_ + tid*4) = s;
    }
  } else if (blk < 56){
    if (t == 0) return;
    int ob = blk - 32;
    int b = tid & 31, rr = (tid>>5)&3, ks = tid>>7;
    int r = ob*4 + rr;
    const float* wr = (r < OUT_) ? (featw + (size_t)r*1536) : probw;
    const float* h1p = ws + OFF_H1T + (size_t)b*1024;
    const float* acp = ws + OFF_ATTC + (size_t)((t-1)&1)*16384 + (size_t)b*ENC_;
    float acc = 0;
    for (int j = ks*96; j < ks*96+96; j++){
      int k = j*4;
      float4 xv = (k < 1024) ? *(const float4*)(h1p + k) : *(const float4*)(acp + (k-1024));
      float4 wv = *(const float4*)(wr + k);
      acc += xv.x*wv.x + xv.y*wv.y + xv.z*wv.z + xv.w*wv.w;
    }
    redo[(rr*4+ks)*32 + b] = acc;
    __syncthreads();
    if (tid < 128){
      int b2 = tid & 31, r2 = tid >> 5;
      float v = 0;
      #pragma unroll
      for (int k2=0;k2<4;k2++) v += redo[(r2*4+k2)*32 + b2];
      int rr2 = ob*4 + r2, tt = t-1;
      if (rr2 < OUT_) out[((size_t)b2*OUT_ + rr2)*TD_ + tt] = v;
      else if (rr2 == OUT_) out[LOG_OFF + (size_t)b2*TD_ + tt] = v + probb[0];
    }
  } else {
    int idx = (blk-56)*4096 + tid*8;
    int bb = idx >> 10, u = idx & 1023;
    *(float4*)(ws + OFF_XC1 + (size_t)bb*2048 + 1024 + u) = *(const float4*)(ws + OFF_H1T + idx);
    *(float4*)(ws + OFF_XC1 + (size_t)bb*2048 + 1024 + u + 4) = *(const float4*)(ws + OFF_H1T + idx + 4);
  }
}

// B: LSTM0. grid 512, block owns units u0=blk*2 (+1), 8 gate-rows. K=1792.
__global__ __launch_bounds__(512) void k_lstm0(int t,
    const float* __restrict__ wih, const float* __restrict__ whh,
    const float* __restrict__ bih, const float* __restrict__ bhh, float* __restrict__ ws){
  __shared__ __align__(16) float wlds[8*1792];
  float* redp = wlds;   // aliased scratch (used only after a sync)
  int tid = threadIdx.x;
  int u0 = blockIdx.x*2;
  for (int i=tid; i<8*448; i+=512){
    int rw = i/448, c4 = (i%448)*4;
    int grow = (rw>>1)*1024 + u0 + (rw&1);
    float4 w = (c4 < 768) ? *(const float4*)(wih + (size_t)grow*768 + c4)
                          : *(const float4*)(whh + (size_t)grow*1024 + (c4-768));
    *(float4*)(wlds + rw*1792 + c4) = w;
  }
  __syncthreads();
  int bp = tid & 15, ksl = (tid>>4)&3, rg = (tid>>6)&1, ksh = tid>>7;
  int kbase = (ksh*4 + ksl)*112;
  const float* x0 = ws + OFF_XC0 + (size_t)bp*1792;
  const float* x1 = ws + OFF_XC0 + (size_t)(bp+16)*1792;
  const float* wp = wlds + rg*4*1792;
  float a0[4]={0,0,0,0}, a1[4]={0,0,0,0};
  for (int kc=0; kc<112; kc+=16){
    float4 xa[4], xb[4];
    #pragma unroll
    for (int j=0;j<4;j++){
      xa[j] = *(const float4*)(x0 + kbase + kc + j*4);
      xb[j] = *(const float4*)(x1 + kbase + kc + j*4);
    }
    #pragma unroll
    for (int j=0;j<4;j++){
      #pragma unroll
      for (int rr=0;rr<4;rr++){
        float4 w = *(const float4*)(wp + rr*1792 + kbase + kc + j*4);
        a0[rr] += w.x*xa[j].x + w.y*xa[j].y + w.z*xa[j].z + w.w*xa[j].w;
        a1[rr] += w.x*xb[j].x + w.y*xb[j].y + w.z*xb[j].z + w.w*xb[j].w;
      }
    }
  }
  #pragma unroll
  for (int rr=0;rr<4;rr++){
    a0[rr] += __shfl_xor(a0[rr],16); a0[rr] += __shfl_xor(a0[rr],32);
    a1[rr] += __shfl_xor(a1[rr],16); a1[rr] += __shfl_xor(a1[rr],32);
  }
  __syncthreads();          // all wlds reads done before alias reuse
  if (ksl == 0){
    #pragma unroll
    for (int rr=0;rr<4;rr++){
      int rw = rg*4 + rr;
      redp[(rw*32 + bp)*4 + ksh]      = a0[rr];
      redp[(rw*32 + bp+16)*4 + ksh]   = a1[rr];
    }
  }
  __syncthreads();
  if (tid < 64){
    int b = tid & 31, uu = tid >> 5;
    int u = u0 + uu;
    float gv[4];
    #pragma unroll
    for (int g=0; g<4; g++){
      int rw = g*2 + uu;
      float s = 0;
      #pragma unroll
      for (int kg=0;kg<4;kg++) s += redp[(rw*32 + b)*4 + kg];
      gv[g] = s + bih[g*1024+u] + bhh[g*1024+u];
    }
    float c_old = ws[OFF_C0 + (size_t)b*1024 + u];
    float h_old = ws[OFF_XC0 + (size_t)b*1792 + 768 + u];
    float cn = sigm(gv[1])*c_old + sigm(gv[0])*tanh_f(gv[2]);
    float hn = sigm(gv[3])*tanh_f(cn);
    ws[OFF_C0 + (size_t)b*1024 + u] = 0.1f*c_old + 0.9f*cn;
    ws[OFF_XC1 + (size_t)b*2048 + u] = 0.1f*h_old + 0.9f*hn;
  }
}

// C: LSTM1 (grid 512, units u0=blk*2) + Wh (blocks<128) + h0 copy. K=2048.
__global__ __launch_bounds__(512) void k_lstm1(int t,
    const float* __restrict__ wih, const float* __restrict__ whh,
    const float* __restrict__ bih, const float* __restrict__ bhh,
    const float* __restrict__ Ww, float* __restrict__ ws){
  __shared__ __align__(16) float wlds[8*2048];
  float* redp = wlds;
  int tid = threadIdx.x;
  int u0 = blockIdx.x*2;
  for (int i=tid; i<8*512; i+=512){
    int rw = i >> 9;
    int k  = (i & 511)*4;
    int grow = (rw>>1)*1024 + u0 + (rw&1);
    float4 w = (k < 1024) ? *(const float4*)(wih + (size_t)grow*1024 + k)
                          : *(const float4*)(whh + (size_t)grow*1024 + (k-1024));
    int kk = k ^ (((k>>7)&7)<<2);
    *(float4*)(wlds + rw*2048 + kk) = w;
  }
  __syncthreads();
  int bp = tid & 15, ksl = (tid>>4)&3, rg = (tid>>6)&1, ksh = tid>>7;
  int ks = ksh*4 + ksl;
  int kbase = ks*128;
  int swz = (ks&7)<<2;
  const float* x0 = ws + OFF_XC1 + (size_t)bp*2048;
  const float* x1 = ws + OFF_XC1 + (size_t)(bp+16)*2048;
  const float* wp = wlds + rg*4*2048;
  float a0[4]={0,0,0,0}, a1[4]={0,0,0,0};
  for (int kc=0; kc<128; kc+=16){
    float4 xa[4], xb[4];
    #pragma unroll
    for (int j=0;j<4;j++){
      xa[j] = *(const float4*)(x0 + kbase + kc + j*4);
      xb[j] = *(const float4*)(x1 + kbase + kc + j*4);
    }
    #pragma unroll
    for (int j=0;j<4;j++){
      #pragma unroll
      for (int rr=0;rr<4;rr++){
        float4 w = *(const float4*)(wp + rr*2048 + ((kbase + kc + j*4) ^ swz));
        a0[rr] += w.x*xa[j].x + w.y*xa[j].y + w.z*xa[j].z + w.w*xa[j].w;
        a1[rr] += w.x*xb[j].x + w.y*xb[j].y + w.z*xb[j].z + w.w*xb[j].w;
      }
    }
  }
  #pragma unroll
  for (int rr=0;rr<4;rr++){
    a0[rr] += __shfl_xor(a0[rr],16); a0[rr] += __shfl_xor(a0[rr],32);
    a1[rr] += __shfl_xor(a1[rr],16); a1[rr] += __shfl_xor(a1[rr],32);
  }
  __syncthreads();
  if (ksl == 0){
    #pragma unroll
    for (int rr=0;rr<4;rr++){
      int rw = rg*4 + rr;
      redp[(rw*32 + bp)*4 + ksh]    = a0[rr];
      redp[(rw*32 + bp+16)*4 + ksh] = a1[rr];
    }
  }
  __syncthreads();
  if (tid < 64){
    int b = tid & 31, uu = tid >> 5;
    int u = u0 + uu;
    float gv[4];
    #pragma unroll
    for (int g=0; g<4; g++){
      int rw = g*2 + uu;
      float s = 0;
      #pragma unroll
      for (int kg=0;kg<4;kg++) s += redp[(rw*32 + b)*4 + kg];
      gv[g] = s + bih[g*1024+u] + bhh[g*1024+u];
    }
    float c_old = ws[OFF_C1 + (size_t)b*1024 + u];
    float h_old = ws[OFF_XC1 + (size_t)b*2048 + 1024 + u];
    float cn = sigm(gv[1])*c_old + sigm(gv[0])*tanh_f(gv[2]);
    float hn = sigm(gv[3])*tanh_f(cn);
    ws[OFF_C1 + (size_t)b*1024 + u] = 0.1f*c_old + 0.9f*cn;
    ws[OFF_H1T + (size_t)b*1024 + u] = 0.1f*h_old + 0.9f*hn;
    // stage h0 (zoneouted) into XC0 for next step's lstm0
    ws[OFF_XC0 + (size_t)b*1792 + 768 + u] = ws[OFF_XC1 + (size_t)b*2048 + u];
  }
  if (blockIdx.x < 128){
    int a = blockIdx.x;
    int b3 = tid & 31, q = tid >> 5;
    float s = 0;
    for (int k = q*64; k < q*64+64; k += 4){
      float4 xv = *(const float4*)(ws + OFF_XC1 + (size_t)b3*2048 + k);
      float4 wv = *(const float4*)(Ww + (size_t)a*1024 + k);
      s += xv.x*wv.x + xv.y*wv.y + xv.z*wv.z + xv.w*wv.w;
    }
    __syncthreads();
    redp[q*32 + b3] = s;
    __syncthreads();
    if (tid < 32){
      float s2 = 0;
      #pragma unroll
      for (int q2=0;q2<16;q2++) s2 += redp[q2*32 + tid];
      ws[OFF_WH + (size_t)tid*128 + a] = s2;
    }
  }
}

extern "C" void kernel_launch(void* const* d_in, const int* in_sizes, int n_in,
                              void* d_out, int out_size, void* d_ws, size_t ws_size,
                              hipStream_t stream){
  const float* enc   = (const float*)d_in[0];
  const float* tgt   = (const float*)d_in[1];
  const float* masks = (const float*)d_in[2];
  const int*   lens  = (const int*)  d_in[3];
  const float* Vw    = (const float*)d_in[4];
  const float* Vb    = (const float*)d_in[5];
  const float* Ww    = (const float*)d_in[6];
  const float* Uw    = (const float*)d_in[7];
  const float* Fw    = (const float*)d_in[8];
  const float* ww    = (const float*)d_in[9];
  const float* wb    = (const float*)d_in[10];
  const float* pw0   = (const float*)d_in[11];
  const float* pb0   = (const float*)d_in[12];
  const float* pw1   = (const float*)d_in[13];
  const float* pb1   = (const float*)d_in[14];
  const float* l0wih = (const float*)d_in[15];
  const float* l0whh = (const float*)d_in[16];
  const float* l0bih = (const float*)d_in[17];
  const float* l0bhh = (const float*)d_in[18];
  const float* l1wih = (const float*)d_in[19];
  const float* l1whh = (const float*)d_in[20];
  const float* l1bih = (const float*)d_in[21];
  const float* l1bhh = (const float*)d_in[22];
  const float* featw = (const float*)d_in[23];
  const float* probw = (const float*)d_in[24];
  const float* probb = (const float*)d_in[25];
  float* ws  = (float*)d_ws;
  float* out = (float*)d_out;

  k_pre0 <<<256,256,0,stream>>>(tgt, pw0, pb0, masks, ws);
  k_pre1 <<<256,256,0,stream>>>(pw1, pb1, masks, ws);
  k_precm<<<1,  256,0,stream>>>(Uw, Fw, ws);
  k_init <<<256,256,0,stream>>>(ws);
  k_pm   <<<128,256,0,stream>>>(enc, Vw, Vb, ws);

  for (int t = 0; t < TD_; t++){
    k_att  <<<64, 512,0,stream>>>(t, enc, lens, ww, wb, featw, probw, probb, ws, out);
    k_lstm0<<<512,512,0,stream>>>(t, l0wih, l0whh, l0bih, l0bhh, ws);
    k_lstm1<<<512,512,0,stream>>>(t, l1wih, l1whh, l1bih, l1bhh, Ww, ws);
  }
  k_att<<<64,512,0,stream>>>(TD_, enc, lens, ww, wb, featw, probw, probb, ws, out);
}